// Round 3
// baseline (182.753 us; speedup 1.0000x reference)
//
#include <hip/hip_runtime.h>
#include <stdint.h>

#define T_TOK 8192   // B*S
#define DD    1024   // D
#define EN    8      // experts
#define CPAD  16     // ints per expert counter slot (64 B each)

#define BM 256
#define BN 256
#define BK 64
#define NWG 1024     // 4 N-tiles * 32 M-tiles * 8 experts (full coverage, early-exit)

typedef __bf16 v8bf __attribute__((ext_vector_type(8)));
typedef float  v4f  __attribute__((ext_vector_type(4)));

__device__ __forceinline__ uint16_t f2b(float f) {
  uint32_t u = __builtin_bit_cast(uint32_t, f);
  u += 0x7FFFu + ((u >> 16) & 1u);          // round-to-nearest-even
  return (uint16_t)(u >> 16);
}

// ---------- Phase 1: gating (fp64 logits), block-aggregated routing, x -> bf16 ----------
__global__ __launch_bounds__(256) void gate_route_kernel(
    const float* __restrict__ x, const float* __restrict__ gw,
    const float* __restrict__ gb, uint16_t* __restrict__ xb,
    int* __restrict__ counts, int* __restrict__ lists) {
  __shared__ float sgw[DD * EN];   // 32 KB, [d][e]
  __shared__ float sx[4][DD];      // 16 KB, one token per wave
  __shared__ int se1[32], se2[32];
  const int tid = threadIdx.x;
#pragma unroll
  for (int i = 0; i < 32; ++i) sgw[i * 256 + tid] = gw[i * 256 + tid];
  const int t0 = blockIdx.x * 32;
  const int wid = tid >> 6, lane = tid & 63;
  const int e = lane >> 3, dg = lane & 7;   // lane = (expert, d-group)

  for (int r = 0; r < 8; ++r) {
    const int tt = t0 + wid * 8 + r;
    const float4* xg = (const float4*)(x + (size_t)tt * DD);
    float4* sxv = (float4*)sx[wid];
    ushort4* xbv = (ushort4*)(xb + (size_t)tt * DD);
#pragma unroll
    for (int i = 0; i < 4; ++i) {
      float4 v = xg[i * 64 + lane];
      sxv[i * 64 + lane] = v;
      ushort4 h;
      h.x = f2b(v.x); h.y = f2b(v.y); h.z = f2b(v.z); h.w = f2b(v.w);
      xbv[i * 64 + lane] = h;
    }
    __syncthreads();

    const float* xr = sx[wid];
    double a0 = 0.0, a1 = 0.0, a2 = 0.0, a3 = 0.0;
#pragma unroll 8
    for (int k = 0; k < 128; k += 4) {
      int d = dg + k * 8;
      a0 += (double)xr[d]      * (double)sgw[d * 8 + e];
      a1 += (double)xr[d + 8]  * (double)sgw[(d + 8) * 8 + e];
      a2 += (double)xr[d + 16] * (double)sgw[(d + 16) * 8 + e];
      a3 += (double)xr[d + 24] * (double)sgw[(d + 24) * 8 + e];
    }
    double acc = (a0 + a1) + (a2 + a3);
#pragma unroll
    for (int off = 1; off < 8; off <<= 1) acc += __shfl_xor(acc, off);
    acc += (double)gb[e];
    double lg[8];
#pragma unroll
    for (int i = 0; i < 8; ++i) lg[i] = __shfl(acc, i * 8);
    if (lane == 0) {
      int e1 = 0; double m1 = lg[0];
#pragma unroll
      for (int i = 1; i < 8; ++i) if (lg[i] > m1) { m1 = lg[i]; e1 = i; }
      int e2 = 0; double m2 = -1.0e300;
#pragma unroll
      for (int i = 0; i < 8; ++i) if (i != e1 && lg[i] > m2) { m2 = lg[i]; e2 = i; }
      se1[wid * 8 + r] = e1;
      se2[wid * 8 + r] = e2;
    }
    __syncthreads();
  }

  if (tid < EN) {
    int cnt = 0;
#pragma unroll
    for (int i = 0; i < 32; ++i) cnt += (se1[i] == tid) + (se2[i] == tid);
    int base = atomicAdd(&counts[tid * CPAD], cnt);
    int* dst = lists + tid * T_TOK;
    for (int i = 0; i < 32; ++i) {
      if (se1[i] == tid) dst[base++] = t0 + i;
      if (se2[i] == tid) dst[base++] = t0 + i;
    }
  }
}

// ---------- Phase 2: expert_w [e][d][f] fp32 -> Wt [e][f][d] bf16 ----------
__global__ __launch_bounds__(256) void wt_transpose_kernel(
    const float* __restrict__ w, uint16_t* __restrict__ wt) {
  __shared__ float tile[64][65];
  const int e = blockIdx.z;
  const int f0 = blockIdx.x * 64, d0 = blockIdx.y * 64;
  const float* wsrc = w + ((size_t)e << 20);
  uint16_t* wdst = wt + ((size_t)e << 20);
  const int r = threadIdx.x >> 6, c = threadIdx.x & 63;
#pragma unroll
  for (int i = 0; i < 16; ++i) {
    int row = i * 4 + r;
    tile[row][c] = wsrc[(size_t)(d0 + row) * DD + f0 + c];
  }
  __syncthreads();
#pragma unroll
  for (int i = 0; i < 16; ++i) {
    int frow = i * 4 + r;
    wdst[(size_t)(f0 + frow) * DD + d0 + c] = f2b(tile[c][frow]);
  }
}

// ---------- Phase 3: gathered per-expert GEMM, 256x256 tile, 8 waves ----------
// XCD chunked swizzle: expert k -> XCD k (its wt fits that XCD's 4MB L2; the 4
// co-started N-blocks of an M-panel share the A-panel in L2).
// LDS bank-swizzle: linear LDS dest (global_load_lds constraint) + pre-swizzled
// GLOBAL source k-offset + matching XOR on ds_read (both-sides involution).
__global__ __launch_bounds__(512, 2) void expert_gemm_kernel(
    const uint16_t* __restrict__ xb, const uint16_t* __restrict__ wt,
    const float* __restrict__ eb, const int* __restrict__ counts,
    const int* __restrict__ lists, float* __restrict__ out) {
  const int orig = blockIdx.x;
  const int wgid = (orig & 7) * (NWG / 8) + (orig >> 3);  // bijective chunked
  const int e = wgid >> 7;          // 128 wgids per expert
  const int rem = wgid & 127;
  const int m0 = (rem >> 2) * BM;
  const int n0 = (rem & 3) * BN;
  const int cnt = counts[e * CPAD];
  if (m0 >= cnt) return;
  int rows = cnt - m0; if (rows > BM) rows = BM;

  __shared__ uint16_t sA[BM * BK];  // 32 KB, linear [row][64], data k-swizzled
  __shared__ uint16_t sB[BN * BK];  // 32 KB
  __shared__ int toks[BM];

  const int tid = threadIdx.x;
  if (tid < BM) {
    int rr = tid < rows ? tid : 0;
    toks[tid] = lists[e * T_TOK + m0 + rr];
  }
  __syncthreads();

  const int lane = tid & 63;
  const int wid = tid >> 6;        // 0..7
  const int wm = wid >> 2;         // 0..1  (M half: 128 rows)
  const int wn = wid & 3;          // 0..3  (N quarter: 64 cols)

  v4f acc[8][4];
#pragma unroll
  for (int i = 0; i < 8; ++i)
#pragma unroll
    for (int j = 0; j < 4; ++j) acc[i][j] = (v4f){0.f, 0.f, 0.f, 0.f};

  // Staging: idx = i*512+tid; row = idx>>3; 8 lanes x 16B cover one row's 128B.
  // Source k-offset XOR-swizzled by (row&7)<<3 elements.
  const uint16_t* aptr[4];
  const uint16_t* bptr[4];
  const uint16_t* wte = wt + ((size_t)e << 20) + (size_t)n0 * DD;
#pragma unroll
  for (int i = 0; i < 4; ++i) {
    int idx = i * 512 + tid;
    int row = idx >> 3;
    int koff = (((idx & 7) << 3) ^ ((row & 7) << 3));
    aptr[i] = xb + (size_t)toks[row] * DD + koff;
    bptr[i] = wte + (size_t)row * DD + koff;
  }

  for (int kt = 0; kt < DD / BK; ++kt) {
    const int k0 = kt * BK;
#pragma unroll
    for (int i = 0; i < 4; ++i) {
      int idx = i * 512 + tid;
      __builtin_amdgcn_global_load_lds(
          (const __attribute__((address_space(1))) uint32_t*)(aptr[i] + k0),
          (__attribute__((address_space(3))) uint32_t*)(sA + idx * 8), 16, 0, 0);
    }
#pragma unroll
    for (int i = 0; i < 4; ++i) {
      int idx = i * 512 + tid;
      __builtin_amdgcn_global_load_lds(
          (const __attribute__((address_space(1))) uint32_t*)(bptr[i] + k0),
          (__attribute__((address_space(3))) uint32_t*)(sB + idx * 8), 16, 0, 0);
    }
    __syncthreads();

#pragma unroll
    for (int kk = 0; kk < 2; ++kk) {
      const int roff = (kk * 32 + (lane >> 4) * 8) ^ ((lane & 7) << 3);
      v8bf af[8], bfr[4];
#pragma unroll
      for (int m = 0; m < 8; ++m)
        af[m] = *(const v8bf*)(sA + (wm * 128 + m * 16 + (lane & 15)) * BK + roff);
#pragma unroll
      for (int n = 0; n < 4; ++n)
        bfr[n] = *(const v8bf*)(sB + (wn * 64 + n * 16 + (lane & 15)) * BK + roff);
#pragma unroll
      for (int m = 0; m < 8; ++m)
#pragma unroll
        for (int n = 0; n < 4; ++n)
          acc[m][n] = __builtin_amdgcn_mfma_f32_16x16x32_bf16(
              af[m], bfr[n], acc[m][n], 0, 0, 0);
    }
    __syncthreads();
  }

  // Epilogue: C/D layout col=lane&15, row=(lane>>4)*4+j.
  const int col = lane & 15, rq = lane >> 4;
  float biasv[4];
#pragma unroll
  for (int n = 0; n < 4; ++n)
    biasv[n] = eb[e * DD + n0 + wn * 64 + n * 16 + col];
#pragma unroll
  for (int m = 0; m < 8; ++m) {
#pragma unroll
    for (int j = 0; j < 4; ++j) {
      int trow = wm * 128 + m * 16 + rq * 4 + j;
      if (trow < rows) {
        float* orow = out + (size_t)toks[trow] * DD + n0;
#pragma unroll
        for (int n = 0; n < 4; ++n) {
          int tcol = wn * 64 + n * 16 + col;
          atomicAdd(orow + tcol, acc[m][n][j] + biasv[n]);
        }
      }
    }
  }
}

extern "C" void kernel_launch(void* const* d_in, const int* in_sizes, int n_in,
                              void* d_out, int out_size, void* d_ws, size_t ws_size,
                              hipStream_t stream) {
  const float* x  = (const float*)d_in[0];   // [4,2048,1024] f32
  const float* gw = (const float*)d_in[1];   // [1024,8] f32
  const float* gb = (const float*)d_in[2];   // [8] f32
  const float* ew = (const float*)d_in[3];   // [8,1024,1024] f32
  const float* ebias = (const float*)d_in[4];// [8,1024] f32
  float* out = (float*)d_out;                // [4,2048,1024] f32

  uint8_t* ws = (uint8_t*)d_ws;
  int* counts = (int*)ws;                                   // 512 B
  int* lists  = (int*)(ws + 512);                           // 256 KiB
  uint16_t* xb = (uint16_t*)(ws + 512 + 262144);            // 16 MiB bf16 x
  uint16_t* wt = (uint16_t*)(ws + 512 + 262144 + 16777216); // 16 MiB bf16 W^T

  hipMemsetAsync(counts, 0, 512, stream);
  hipMemsetAsync(d_out, 0, (size_t)out_size * sizeof(float), stream);

  wt_transpose_kernel<<<dim3(16, 16, EN), 256, 0, stream>>>(ew, wt);
  gate_route_kernel<<<T_TOK / 32, 256, 0, stream>>>(x, gw, gb, xb, counts, lists);
  expert_gemm_kernel<<<NWG, 512, 0, stream>>>(xb, wt, ebias, counts, lists, out);
}

// Round 4
// 140.495 us; speedup vs baseline: 1.3008x; 1.3008x over previous
//
#include <hip/hip_runtime.h>
#include <stdint.h>

#define T_TOK 8192   // B*S
#define DD    1024   // D
#define EN    8      // experts
#define CPAD  16     // ints per expert counter slot (64 B each)

#define BM 256
#define BN 256
#define BK 64
#define NT (DD / BK)   // 16 K-steps
#define NWG 1024       // 4 N-tiles * 32 M-tile slots * 8 experts (early-exit)

typedef __bf16 v8bf __attribute__((ext_vector_type(8)));
typedef float  v4f  __attribute__((ext_vector_type(4)));

__device__ __forceinline__ uint16_t f2b(float f) {
  uint32_t u = __builtin_bit_cast(uint32_t, f);
  u += 0x7FFFu + ((u >> 16) & 1u);          // round-to-nearest-even
  return (uint16_t)(u >> 16);
}

// ---------- Phase 1: gating (fp64 logits), block-aggregated routing, x -> bf16 ----------
// Also records pidx[t] = {e1*T_TOK+pos1, e2*T_TOK+pos2} for the positional epilogue.
template <bool WRITE_PIDX>
__global__ __launch_bounds__(256) void gate_route_kernel(
    const float* __restrict__ x, const float* __restrict__ gw,
    const float* __restrict__ gb, uint16_t* __restrict__ xb,
    int* __restrict__ counts, int* __restrict__ lists, int* __restrict__ pidx) {
  __shared__ float sgw[DD * EN];   // 32 KB, [d][e]
  __shared__ float sx[4][DD];      // 16 KB, one token per wave
  __shared__ int se1[32], se2[32];
  const int tid = threadIdx.x;
#pragma unroll
  for (int i = 0; i < 32; ++i) sgw[i * 256 + tid] = gw[i * 256 + tid];
  const int t0 = blockIdx.x * 32;
  const int wid = tid >> 6, lane = tid & 63;
  const int e = lane >> 3, dg = lane & 7;   // lane = (expert, d-group)

  for (int r = 0; r < 8; ++r) {
    const int tt = t0 + wid * 8 + r;
    const float4* xg = (const float4*)(x + (size_t)tt * DD);
    float4* sxv = (float4*)sx[wid];
    ushort4* xbv = (ushort4*)(xb + (size_t)tt * DD);
#pragma unroll
    for (int i = 0; i < 4; ++i) {
      float4 v = xg[i * 64 + lane];
      sxv[i * 64 + lane] = v;
      ushort4 h;
      h.x = f2b(v.x); h.y = f2b(v.y); h.z = f2b(v.z); h.w = f2b(v.w);
      xbv[i * 64 + lane] = h;
    }
    __syncthreads();

    const float* xr = sx[wid];
    double a0 = 0.0, a1 = 0.0, a2 = 0.0, a3 = 0.0;
#pragma unroll 8
    for (int k = 0; k < 128; k += 4) {
      int d = dg + k * 8;
      a0 += (double)xr[d]      * (double)sgw[d * 8 + e];
      a1 += (double)xr[d + 8]  * (double)sgw[(d + 8) * 8 + e];
      a2 += (double)xr[d + 16] * (double)sgw[(d + 16) * 8 + e];
      a3 += (double)xr[d + 24] * (double)sgw[(d + 24) * 8 + e];
    }
    double acc = (a0 + a1) + (a2 + a3);
#pragma unroll
    for (int off = 1; off < 8; off <<= 1) acc += __shfl_xor(acc, off);
    acc += (double)gb[e];
    double lg[8];
#pragma unroll
    for (int i = 0; i < 8; ++i) lg[i] = __shfl(acc, i * 8);
    if (lane == 0) {
      int e1 = 0; double m1 = lg[0];
#pragma unroll
      for (int i = 1; i < 8; ++i) if (lg[i] > m1) { m1 = lg[i]; e1 = i; }
      int e2 = 0; double m2 = -1.0e300;
#pragma unroll
      for (int i = 0; i < 8; ++i) if (i != e1 && lg[i] > m2) { m2 = lg[i]; e2 = i; }
      se1[wid * 8 + r] = e1;
      se2[wid * 8 + r] = e2;
    }
    __syncthreads();
  }

  if (tid < EN) {
    int cnt = 0;
#pragma unroll
    for (int i = 0; i < 32; ++i) cnt += (se1[i] == tid) + (se2[i] == tid);
    int base = atomicAdd(&counts[tid * CPAD], cnt);
    int* dst = lists + tid * T_TOK;
    for (int i = 0; i < 32; ++i) {
      if (se1[i] == tid) {
        if (WRITE_PIDX) pidx[2 * (t0 + i)] = tid * T_TOK + base;
        dst[base++] = t0 + i;
      }
      if (se2[i] == tid) {
        if (WRITE_PIDX) pidx[2 * (t0 + i) + 1] = tid * T_TOK + base;
        dst[base++] = t0 + i;
      }
    }
  }
}

// ---------- Phase 2: expert_w [e][d][f] fp32 -> Wt [e][f][d] bf16 ----------
__global__ __launch_bounds__(256) void wt_transpose_kernel(
    const float* __restrict__ w, uint16_t* __restrict__ wt) {
  __shared__ float tile[64][65];
  const int e = blockIdx.z;
  const int f0 = blockIdx.x * 64, d0 = blockIdx.y * 64;
  const float* wsrc = w + ((size_t)e << 20);
  uint16_t* wdst = wt + ((size_t)e << 20);
  const int r = threadIdx.x >> 6, c = threadIdx.x & 63;
#pragma unroll
  for (int i = 0; i < 16; ++i) {
    int row = i * 4 + r;
    tile[row][c] = wsrc[(size_t)(d0 + row) * DD + f0 + c];
  }
  __syncthreads();
#pragma unroll
  for (int i = 0; i < 16; ++i) {
    int frow = i * 4 + r;
    wdst[(size_t)(f0 + frow) * DD + d0 + c] = f2b(tile[c][frow]);
  }
}

// ---------- Phase 3: gathered per-expert GEMM, 256x256, dbuf-prefetch 2-phase ----------
// ATOMIC=false: streaming stores into compacted wsO rows (no atomics, combine adds bias).
// ATOMIC=true : legacy fallback (atomicAdd into out, bias folded) if ws too small.
template <bool ATOMIC>
__global__ __launch_bounds__(512, 2) void expert_gemm_kernel(
    const uint16_t* __restrict__ xb, const uint16_t* __restrict__ wt,
    const float* __restrict__ eb, const int* __restrict__ counts,
    const int* __restrict__ lists, float* __restrict__ dst) {
  const int orig = blockIdx.x;
  const int wgid = (orig & 7) * (NWG / 8) + (orig >> 3);  // expert k -> XCD k
  const int e = wgid >> 7;
  const int rem = wgid & 127;
  const int m0 = (rem >> 2) * BM;
  const int n0 = (rem & 3) * BN;
  const int cnt = counts[e * CPAD];
  if (m0 >= cnt) return;
  int rows = cnt - m0; if (rows > BM) rows = BM;
  int offsE = 0;
  if (!ATOMIC) {
#pragma unroll
    for (int i = 0; i < EN; ++i) offsE += (i < e) ? counts[i * CPAD] : 0;
  }

  __shared__ uint16_t sA[2 * BM * BK];  // 64 KB double-buffered, linear, k-swizzled data
  __shared__ uint16_t sB[2 * BN * BK];  // 64 KB
  __shared__ int toks[BM];

  const int tid = threadIdx.x;
  if (tid < BM) {
    int rr = tid < rows ? tid : 0;
    toks[tid] = lists[e * T_TOK + m0 + rr];
  }
  __syncthreads();

  const int lane = tid & 63;
  const int wid = tid >> 6;        // 0..7
  const int wm = wid >> 2;         // 0..1  (M half: 128 rows)
  const int wn = wid & 3;          // 0..3  (N quarter: 64 cols)

  v4f acc[8][4];
#pragma unroll
  for (int i = 0; i < 8; ++i)
#pragma unroll
    for (int j = 0; j < 4; ++j) acc[i][j] = (v4f){0.f, 0.f, 0.f, 0.f};

  // Staging: idx = i*512+tid; row = idx>>3; 8 lanes x 16B cover one row's 128B.
  // Global source k-offset XOR-pre-swizzled; ds_read applies the same involution.
  const uint16_t* aptr[4];
  const uint16_t* bptr[4];
  const uint16_t* wte = wt + ((size_t)e << 20) + (size_t)n0 * DD;
#pragma unroll
  for (int i = 0; i < 4; ++i) {
    int idx = i * 512 + tid;
    int row = idx >> 3;
    int koff = (((idx & 7) << 3) ^ ((row & 7) << 3));
    aptr[i] = xb + (size_t)toks[row] * DD + koff;
    bptr[i] = wte + (size_t)row * DD + koff;
  }

#define STAGE(buf, k0)                                                          \
  {                                                                             \
    _Pragma("unroll")                                                           \
    for (int i = 0; i < 4; ++i) {                                               \
      int idx = i * 512 + tid;                                                  \
      __builtin_amdgcn_global_load_lds(                                         \
          (const __attribute__((address_space(1))) uint32_t*)(aptr[i] + (k0)),  \
          (__attribute__((address_space(3))) uint32_t*)(sA + (buf) * (BM * BK) + idx * 8), \
          16, 0, 0);                                                            \
      __builtin_amdgcn_global_load_lds(                                         \
          (const __attribute__((address_space(1))) uint32_t*)(bptr[i] + (k0)),  \
          (__attribute__((address_space(3))) uint32_t*)(sB + (buf) * (BN * BK) + idx * 8), \
          16, 0, 0);                                                            \
    }                                                                           \
  }

  STAGE(0, 0);
  __syncthreads();

  int cur = 0;
  for (int kt = 0; kt < NT; ++kt) {
    if (kt + 1 < NT) STAGE(cur ^ 1, (kt + 1) * BK);   // prefetch flies under MFMA
    const uint16_t* a_base = sA + cur * (BM * BK);
    const uint16_t* b_base = sB + cur * (BN * BK);
#pragma unroll
    for (int kk = 0; kk < 2; ++kk) {
      const int roff = (kk * 32 + (lane >> 4) * 8) ^ ((lane & 7) << 3);
      v8bf af[8], bfr[4];
#pragma unroll
      for (int m = 0; m < 8; ++m)
        af[m] = *(const v8bf*)(a_base + (wm * 128 + m * 16 + (lane & 15)) * BK + roff);
#pragma unroll
      for (int n = 0; n < 4; ++n)
        bfr[n] = *(const v8bf*)(b_base + (wn * 64 + n * 16 + (lane & 15)) * BK + roff);
#pragma unroll
      for (int m = 0; m < 8; ++m)
#pragma unroll
        for (int n = 0; n < 4; ++n)
          acc[m][n] = __builtin_amdgcn_mfma_f32_16x16x32_bf16(
              af[m], bfr[n], acc[m][n], 0, 0, 0);
    }
    __syncthreads();   // drains this iter's prefetch (vmcnt0) + protects cur buf
    cur ^= 1;
  }
#undef STAGE

  // Epilogue: C/D layout col=lane&15, row=(lane>>4)*4+j.
  const int col = lane & 15, rq = lane >> 4;
  if (!ATOMIC) {
    float* base = dst + (size_t)(offsE + m0) * DD + n0 + wn * 64 + col;
#pragma unroll
    for (int m = 0; m < 8; ++m) {
#pragma unroll
      for (int j = 0; j < 4; ++j) {
        int trow = wm * 128 + m * 16 + rq * 4 + j;
        if (trow < rows) {
          float* orow = base + (size_t)trow * DD;
#pragma unroll
          for (int n = 0; n < 4; ++n) orow[n * 16] = acc[m][n][j];
        }
      }
    }
  } else {
    float biasv[4];
#pragma unroll
    for (int n = 0; n < 4; ++n)
      biasv[n] = eb[e * DD + n0 + wn * 64 + n * 16 + col];
#pragma unroll
    for (int m = 0; m < 8; ++m) {
#pragma unroll
      for (int j = 0; j < 4; ++j) {
        int trow = wm * 128 + m * 16 + rq * 4 + j;
        if (trow < rows) {
          float* orow = dst + (size_t)toks[trow] * DD + n0;
#pragma unroll
          for (int n = 0; n < 4; ++n)
            atomicAdd(orow + wn * 64 + n * 16 + col, acc[m][n][j] + biasv[n]);
        }
      }
    }
  }
}

// ---------- Phase 4: combine — out[t] = wsO[row(e1,p1)] + wsO[row(e2,p2)] + b1 + b2 ----------
__global__ __launch_bounds__(256) void combine_kernel(
    const float* __restrict__ wsO, const int* __restrict__ pidx,
    const int* __restrict__ counts, const float* __restrict__ eb,
    float* __restrict__ out) {
  __shared__ int soff[EN];
  const int tid = threadIdx.x;
  if (tid == 0) {
    int o = 0;
#pragma unroll
    for (int i = 0; i < EN; ++i) { soff[i] = o; o += counts[i * CPAD]; }
  }
  __syncthreads();
  const int t0 = blockIdx.x * 4;
#pragma unroll
  for (int r = 0; r < 4; ++r) {
    const int t = t0 + r;
    const int pi1 = pidx[2 * t], pi2 = pidx[2 * t + 1];
    const int e1 = pi1 >> 13, p1 = pi1 & (T_TOK - 1);
    const int e2 = pi2 >> 13, p2 = pi2 & (T_TOK - 1);
    const v4f* r1 = (const v4f*)(wsO + (size_t)(soff[e1] + p1) * DD);
    const v4f* r2 = (const v4f*)(wsO + (size_t)(soff[e2] + p2) * DD);
    const v4f* b1 = (const v4f*)(eb + e1 * DD);
    const v4f* b2 = (const v4f*)(eb + e2 * DD);
    v4f* o = (v4f*)(out + (size_t)t * DD);
    o[tid] = (r1[tid] + r2[tid]) + (b1[tid] + b2[tid]);
  }
}

extern "C" void kernel_launch(void* const* d_in, const int* in_sizes, int n_in,
                              void* d_out, int out_size, void* d_ws, size_t ws_size,
                              hipStream_t stream) {
  const float* x  = (const float*)d_in[0];   // [4,2048,1024] f32
  const float* gw = (const float*)d_in[1];   // [1024,8] f32
  const float* gb = (const float*)d_in[2];   // [8] f32
  const float* ew = (const float*)d_in[3];   // [8,1024,1024] f32
  const float* ebias = (const float*)d_in[4];// [8,1024] f32
  float* out = (float*)d_out;                // [4,2048,1024] f32

  uint8_t* ws = (uint8_t*)d_ws;
  int* counts = (int*)ws;                                    // 512 B
  int* lists  = (int*)(ws + 512);                            // 256 KiB
  int* pidx   = (int*)(ws + 512 + 262144);                   // 64 KiB
  uint16_t* xb = (uint16_t*)(ws + 512 + 262144 + 65536);     // 16 MiB
  uint16_t* wt = (uint16_t*)(ws + 512 + 262144 + 65536 + 16777216); // 16 MiB
  float* wsO  = (float*)(ws + 512 + 262144 + 65536 + 16777216 + 16777216); // 64 MiB
  const size_t need = 512ull + 262144 + 65536 + 16777216 + 16777216 +
                      (size_t)2 * T_TOK * DD * sizeof(float);
  const bool use_ws = ws_size >= need;

  hipMemsetAsync(counts, 0, 512, stream);
  wt_transpose_kernel<<<dim3(16, 16, EN), 256, 0, stream>>>(ew, wt);
  if (use_ws) {
    gate_route_kernel<true><<<T_TOK / 32, 256, 0, stream>>>(
        x, gw, gb, xb, counts, lists, pidx);
    expert_gemm_kernel<false><<<NWG, 512, 0, stream>>>(
        xb, wt, ebias, counts, lists, wsO);
    combine_kernel<<<T_TOK / 4, 256, 0, stream>>>(wsO, pidx, counts, ebias, out);
  } else {
    hipMemsetAsync(d_out, 0, (size_t)out_size * sizeof(float), stream);
    gate_route_kernel<false><<<T_TOK / 32, 256, 0, stream>>>(
        x, gw, gb, xb, counts, lists, pidx);
    expert_gemm_kernel<true><<<NWG, 512, 0, stream>>>(
        xb, wt, ebias, counts, lists, out);
  }
}

// Round 5
// 125.064 us; speedup vs baseline: 1.4613x; 1.1234x over previous
//
#include <hip/hip_runtime.h>
#include <stdint.h>

#define T_TOK 8192   // B*S
#define DD    1024   // D
#define EN    8      // experts
#define CPAD  16     // ints per expert counter slot (64 B each)

#define BM 128
#define BN 128
#define BK 64
#define NT (DD / BK)   // 16 K-steps
#define NWG 4096       // 8 experts * 64 M-slots * 8 N-tiles (early-exit)

typedef __bf16 v8bf __attribute__((ext_vector_type(8)));
typedef float  v4f  __attribute__((ext_vector_type(4)));

__device__ __forceinline__ uint16_t f2b(float f) {
  uint32_t u = __builtin_bit_cast(uint32_t, f);
  u += 0x7FFFu + ((u >> 16) & 1u);          // round-to-nearest-even
  return (uint16_t)(u >> 16);
}
__device__ __forceinline__ float b2f(uint16_t h) {
  uint32_t u = (uint32_t)h << 16;
  return __builtin_bit_cast(float, u);
}

// ---------- Phase 1: gating (fp64 logits), block-aggregated routing, x -> bf16 ----------
// Records pidx[t] = {e1*T_TOK+pos1, e2*T_TOK+pos2} for the positional epilogue.
template <bool WRITE_PIDX>
__global__ __launch_bounds__(256) void gate_route_kernel(
    const float* __restrict__ x, const float* __restrict__ gw,
    const float* __restrict__ gb, uint16_t* __restrict__ xb,
    int* __restrict__ counts, int* __restrict__ lists, int* __restrict__ pidx) {
  __shared__ float sgw[DD * EN];   // 32 KB, [d][e]
  __shared__ float sx[4][DD];      // 16 KB, one token per wave
  __shared__ int se1[32], se2[32];
  const int tid = threadIdx.x;
#pragma unroll
  for (int i = 0; i < 32; ++i) sgw[i * 256 + tid] = gw[i * 256 + tid];
  const int t0 = blockIdx.x * 32;
  const int wid = tid >> 6, lane = tid & 63;
  const int e = lane >> 3, dg = lane & 7;   // lane = (expert, d-group)

  for (int r = 0; r < 8; ++r) {
    const int tt = t0 + wid * 8 + r;
    const float4* xg = (const float4*)(x + (size_t)tt * DD);
    float4* sxv = (float4*)sx[wid];
    ushort4* xbv = (ushort4*)(xb + (size_t)tt * DD);
#pragma unroll
    for (int i = 0; i < 4; ++i) {
      float4 v = xg[i * 64 + lane];
      sxv[i * 64 + lane] = v;
      ushort4 h;
      h.x = f2b(v.x); h.y = f2b(v.y); h.z = f2b(v.z); h.w = f2b(v.w);
      xbv[i * 64 + lane] = h;
    }
    __syncthreads();

    const float* xr = sx[wid];
    double a0 = 0.0, a1 = 0.0, a2 = 0.0, a3 = 0.0;
#pragma unroll 8
    for (int k = 0; k < 128; k += 4) {
      int d = dg + k * 8;
      a0 += (double)xr[d]      * (double)sgw[d * 8 + e];
      a1 += (double)xr[d + 8]  * (double)sgw[(d + 8) * 8 + e];
      a2 += (double)xr[d + 16] * (double)sgw[(d + 16) * 8 + e];
      a3 += (double)xr[d + 24] * (double)sgw[(d + 24) * 8 + e];
    }
    double acc = (a0 + a1) + (a2 + a3);
#pragma unroll
    for (int off = 1; off < 8; off <<= 1) acc += __shfl_xor(acc, off);
    acc += (double)gb[e];
    double lg[8];
#pragma unroll
    for (int i = 0; i < 8; ++i) lg[i] = __shfl(acc, i * 8);
    if (lane == 0) {
      int e1 = 0; double m1 = lg[0];
#pragma unroll
      for (int i = 1; i < 8; ++i) if (lg[i] > m1) { m1 = lg[i]; e1 = i; }
      int e2 = 0; double m2 = -1.0e300;
#pragma unroll
      for (int i = 0; i < 8; ++i) if (i != e1 && lg[i] > m2) { m2 = lg[i]; e2 = i; }
      se1[wid * 8 + r] = e1;
      se2[wid * 8 + r] = e2;
    }
    __syncthreads();
  }

  if (tid < EN) {
    int cnt = 0;
#pragma unroll
    for (int i = 0; i < 32; ++i) cnt += (se1[i] == tid) + (se2[i] == tid);
    int base = atomicAdd(&counts[tid * CPAD], cnt);
    int* dst = lists + tid * T_TOK;
    for (int i = 0; i < 32; ++i) {
      if (se1[i] == tid) {
        if (WRITE_PIDX) pidx[2 * (t0 + i)] = tid * T_TOK + base;
        dst[base++] = t0 + i;
      }
      if (se2[i] == tid) {
        if (WRITE_PIDX) pidx[2 * (t0 + i) + 1] = tid * T_TOK + base;
        dst[base++] = t0 + i;
      }
    }
  }
}

// ---------- Phase 2: expert_w [e][d][f] fp32 -> Wt [e][f][d] bf16 ----------
__global__ __launch_bounds__(256) void wt_transpose_kernel(
    const float* __restrict__ w, uint16_t* __restrict__ wt) {
  __shared__ float tile[64][65];
  const int e = blockIdx.z;
  const int f0 = blockIdx.x * 64, d0 = blockIdx.y * 64;
  const float* wsrc = w + ((size_t)e << 20);
  uint16_t* wdst = wt + ((size_t)e << 20);
  const int r = threadIdx.x >> 6, c = threadIdx.x & 63;
#pragma unroll
  for (int i = 0; i < 16; ++i) {
    int row = i * 4 + r;
    tile[row][c] = wsrc[(size_t)(d0 + row) * DD + f0 + c];
  }
  __syncthreads();
#pragma unroll
  for (int i = 0; i < 16; ++i) {
    int frow = i * 4 + r;
    wdst[(size_t)(f0 + frow) * DD + d0 + c] = f2b(tile[c][frow]);
  }
}

// ---------- Phase 3: gathered per-expert GEMM, 128x128, 4 waves, 2 blocks/CU ----------
// expert = orig&7 -> XCD-pinned (wt L2-resident); N fastest within expert for A sharing.
// T2 swizzle: linear LDS dest + pre-swizzled GLOBAL k-offset + matching XOR on ds_read.
// ATOMIC=false: bf16 stores into compacted wsO rows; combine adds bias.
template <bool ATOMIC>
__global__ __launch_bounds__(256, 2) void expert_gemm_kernel(
    const uint16_t* __restrict__ xb, const uint16_t* __restrict__ wt,
    const float* __restrict__ eb, const int* __restrict__ counts,
    const int* __restrict__ lists, uint16_t* __restrict__ dst,
    float* __restrict__ dstf) {
  const int orig = blockIdx.x;
  const int e = orig & 7;               // expert == XCD
  const int rem = orig >> 3;            // 0..511
  const int m0 = (rem >> 3) * BM;
  const int n0 = (rem & 7) * BN;
  const int cnt = counts[e * CPAD];
  if (m0 >= cnt) return;
  int rows = cnt - m0; if (rows > BM) rows = BM;
  int offsE = 0;
  if (!ATOMIC) {
#pragma unroll
    for (int i = 0; i < EN; ++i) offsE += (i < e) ? counts[i * CPAD] : 0;
  }

  __shared__ uint16_t sA[2 * BM * BK];  // 32 KB dbuf, linear, data k-swizzled
  __shared__ uint16_t sB[2 * BN * BK];  // 32 KB
  __shared__ int toks[BM];

  const int tid = threadIdx.x;
  if (tid < BM) {
    int rr = tid < rows ? tid : 0;
    toks[tid] = lists[e * T_TOK + m0 + rr];
  }
  __syncthreads();

  const int lane = tid & 63;
  const int wid = tid >> 6;        // 0..3
  const int wm = wid >> 1;         // 0..1 (64 rows)
  const int wn = wid & 1;          // 0..1 (64 cols)

  v4f acc[4][4];
#pragma unroll
  for (int i = 0; i < 4; ++i)
#pragma unroll
    for (int j = 0; j < 4; ++j) acc[i][j] = (v4f){0.f, 0.f, 0.f, 0.f};

  // Staging: idx = i*256+tid; row = idx>>3; 8 lanes x 16B cover one row's 128B.
  const uint16_t* aptr[4];
  const uint16_t* bptr[4];
  const uint16_t* wte = wt + ((size_t)e << 20) + (size_t)n0 * DD;
#pragma unroll
  for (int i = 0; i < 4; ++i) {
    int idx = i * 256 + tid;
    int row = idx >> 3;
    int koff = (((idx & 7) << 3) ^ ((row & 7) << 3));
    aptr[i] = xb + (size_t)toks[row] * DD + koff;
    bptr[i] = wte + (size_t)row * DD + koff;
  }

#define STAGE(buf, k0)                                                          \
  {                                                                             \
    _Pragma("unroll")                                                           \
    for (int i = 0; i < 4; ++i) {                                               \
      int idx = i * 256 + tid;                                                  \
      __builtin_amdgcn_global_load_lds(                                         \
          (const __attribute__((address_space(1))) uint32_t*)(aptr[i] + (k0)),  \
          (__attribute__((address_space(3))) uint32_t*)(sA + (buf) * (BM * BK) + idx * 8), \
          16, 0, 0);                                                            \
      __builtin_amdgcn_global_load_lds(                                         \
          (const __attribute__((address_space(1))) uint32_t*)(bptr[i] + (k0)),  \
          (__attribute__((address_space(3))) uint32_t*)(sB + (buf) * (BN * BK) + idx * 8), \
          16, 0, 0);                                                            \
    }                                                                           \
  }

  STAGE(0, 0);
  __syncthreads();

  int cur = 0;
  for (int kt = 0; kt < NT; ++kt) {
    if (kt + 1 < NT) STAGE(cur ^ 1, (kt + 1) * BK);   // prefetch flies under MFMA
    const uint16_t* a_base = sA + cur * (BM * BK);
    const uint16_t* b_base = sB + cur * (BN * BK);
#pragma unroll
    for (int kk = 0; kk < 2; ++kk) {
      const int roff = (kk * 32 + (lane >> 4) * 8) ^ ((lane & 7) << 3);
      v8bf af[4], bfr[4];
#pragma unroll
      for (int m = 0; m < 4; ++m)
        af[m] = *(const v8bf*)(a_base + (wm * 64 + m * 16 + (lane & 15)) * BK + roff);
#pragma unroll
      for (int n = 0; n < 4; ++n)
        bfr[n] = *(const v8bf*)(b_base + (wn * 64 + n * 16 + (lane & 15)) * BK + roff);
#pragma unroll
      for (int m = 0; m < 4; ++m)
#pragma unroll
        for (int n = 0; n < 4; ++n)
          acc[m][n] = __builtin_amdgcn_mfma_f32_16x16x32_bf16(
              af[m], bfr[n], acc[m][n], 0, 0, 0);
    }
    __syncthreads();   // drains this iter's prefetch + protects cur buf
    cur ^= 1;
  }
#undef STAGE

  // Epilogue: C/D layout col=lane&15, row=(lane>>4)*4+j.
  const int col = lane & 15, rq = lane >> 4;
  if (!ATOMIC) {
    uint16_t* base = dst + (size_t)(offsE + m0) * DD + n0 + wn * 64 + col;
#pragma unroll
    for (int m = 0; m < 4; ++m) {
#pragma unroll
      for (int j = 0; j < 4; ++j) {
        int trow = wm * 64 + m * 16 + rq * 4 + j;
        if (trow < rows) {
          uint16_t* orow = base + (size_t)trow * DD;
#pragma unroll
          for (int n = 0; n < 4; ++n) orow[n * 16] = f2b(acc[m][n][j]);
        }
      }
    }
  } else {
    float biasv[4];
#pragma unroll
    for (int n = 0; n < 4; ++n)
      biasv[n] = eb[e * DD + n0 + wn * 64 + n * 16 + col];
#pragma unroll
    for (int m = 0; m < 4; ++m) {
#pragma unroll
      for (int j = 0; j < 4; ++j) {
        int trow = wm * 64 + m * 16 + rq * 4 + j;
        if (trow < rows) {
          float* orow = dstf + (size_t)toks[trow] * DD + n0;
#pragma unroll
          for (int n = 0; n < 4; ++n)
            atomicAdd(orow + wn * 64 + n * 16 + col, acc[m][n][j] + biasv[n]);
        }
      }
    }
  }
}

// ---------- Phase 4: combine — out[t] = wsO[row(e1,p1)] + wsO[row(e2,p2)] + b1 + b2 ----------
__global__ __launch_bounds__(256) void combine_kernel(
    const uint16_t* __restrict__ wsO, const int* __restrict__ pidx,
    const int* __restrict__ counts, const float* __restrict__ eb,
    float* __restrict__ out) {
  __shared__ int soff[EN];
  const int tid = threadIdx.x;
  if (tid == 0) {
    int o = 0;
#pragma unroll
    for (int i = 0; i < EN; ++i) { soff[i] = o; o += counts[i * CPAD]; }
  }
  __syncthreads();
  const int t0 = blockIdx.x * 4;
#pragma unroll
  for (int r = 0; r < 4; ++r) {
    const int t = t0 + r;
    const int pi1 = pidx[2 * t], pi2 = pidx[2 * t + 1];
    const int e1 = pi1 >> 13, p1 = pi1 & (T_TOK - 1);
    const int e2 = pi2 >> 13, p2 = pi2 & (T_TOK - 1);
    ushort4 r1 = ((const ushort4*)(wsO + (size_t)(soff[e1] + p1) * DD))[tid];
    ushort4 r2 = ((const ushort4*)(wsO + (size_t)(soff[e2] + p2) * DD))[tid];
    v4f b1 = ((const v4f*)(eb + e1 * DD))[tid];
    v4f b2 = ((const v4f*)(eb + e2 * DD))[tid];
    v4f o;
    o[0] = b2f(r1.x) + b2f(r2.x) + b1[0] + b2[0];
    o[1] = b2f(r1.y) + b2f(r2.y) + b1[1] + b2[1];
    o[2] = b2f(r1.z) + b2f(r2.z) + b1[2] + b2[2];
    o[3] = b2f(r1.w) + b2f(r2.w) + b1[3] + b2[3];
    ((v4f*)(out + (size_t)t * DD))[tid] = o;
  }
}

extern "C" void kernel_launch(void* const* d_in, const int* in_sizes, int n_in,
                              void* d_out, int out_size, void* d_ws, size_t ws_size,
                              hipStream_t stream) {
  const float* x  = (const float*)d_in[0];   // [4,2048,1024] f32
  const float* gw = (const float*)d_in[1];   // [1024,8] f32
  const float* gb = (const float*)d_in[2];   // [8] f32
  const float* ew = (const float*)d_in[3];   // [8,1024,1024] f32
  const float* ebias = (const float*)d_in[4];// [8,1024] f32
  float* out = (float*)d_out;                // [4,2048,1024] f32

  uint8_t* ws = (uint8_t*)d_ws;
  int* counts = (int*)ws;                                    // 512 B
  int* lists  = (int*)(ws + 512);                            // 256 KiB
  int* pidx   = (int*)(ws + 512 + 262144);                   // 64 KiB
  uint16_t* xb = (uint16_t*)(ws + 512 + 262144 + 65536);     // 16 MiB
  uint16_t* wt = (uint16_t*)(ws + 512 + 262144 + 65536 + 16777216); // 16 MiB
  uint16_t* wsO = (uint16_t*)(ws + 512 + 262144 + 65536 + 2 * 16777216); // 32 MiB bf16
  const size_t need = 512ull + 262144 + 65536 + 2 * 16777216 +
                      (size_t)2 * T_TOK * DD * sizeof(uint16_t);
  const bool use_ws = ws_size >= need;

  hipMemsetAsync(counts, 0, 512, stream);
  wt_transpose_kernel<<<dim3(16, 16, EN), 256, 0, stream>>>(ew, wt);
  if (use_ws) {
    gate_route_kernel<true><<<T_TOK / 32, 256, 0, stream>>>(
        x, gw, gb, xb, counts, lists, pidx);
    expert_gemm_kernel<false><<<NWG, 256, 0, stream>>>(
        xb, wt, ebias, counts, lists, wsO, nullptr);
    combine_kernel<<<T_TOK / 4, 256, 0, stream>>>(wsO, pidx, counts, ebias, out);
  } else {
    hipMemsetAsync(d_out, 0, (size_t)out_size * sizeof(float), stream);
    gate_route_kernel<false><<<T_TOK / 32, 256, 0, stream>>>(
        x, gw, gb, xb, counts, lists, pidx);
    expert_gemm_kernel<true><<<NWG, 256, 0, stream>>>(
        xb, wt, ebias, counts, lists, nullptr, out);
  }
}

// Round 6
// 117.384 us; speedup vs baseline: 1.5569x; 1.0654x over previous
//
#include <hip/hip_runtime.h>
#include <stdint.h>

#define T_TOK 8192   // B*S
#define DD    1024   // D
#define EN    8      // experts
#define CPAD  16     // ints per expert counter slot (64 B each)

#define BM 128
#define BN 128
#define BK 32
#define NT (DD / BK)   // 32 K-steps
#define NWG 4096       // 8 experts * 64 M-slots * 8 N-tiles (early-exit)

#define AS1 __attribute__((address_space(1)))
#define AS3 __attribute__((address_space(3)))

typedef __bf16 v8bf __attribute__((ext_vector_type(8)));
typedef float  v4f  __attribute__((ext_vector_type(4)));

__device__ __forceinline__ uint16_t f2b(float f) {
  uint32_t u = __builtin_bit_cast(uint32_t, f);
  u += 0x7FFFu + ((u >> 16) & 1u);          // round-to-nearest-even
  return (uint16_t)(u >> 16);
}
__device__ __forceinline__ float b2f(uint16_t h) {
  uint32_t u = (uint32_t)h << 16;
  return __builtin_bit_cast(float, u);
}

// ---------- Phase 1 (fused): gate blocks [0,256) first (long pole), transpose [256,2304) ----------
// Gate: fp64 logits, block-aggregated routing, x->bf16, pidx for positional epilogue.
// Transpose: expert_w [e][d][f] f32 -> wt [e][f][d] bf16. Independent data => concurrent.
template <bool WRITE_PIDX>
__global__ __launch_bounds__(256) void prep_kernel(
    const float* __restrict__ x, const float* __restrict__ gw,
    const float* __restrict__ gb, uint16_t* __restrict__ xb,
    int* __restrict__ counts, int* __restrict__ lists, int* __restrict__ pidx,
    const float* __restrict__ w, uint16_t* __restrict__ wt) {
  extern __shared__ __align__(16) uint8_t smem[];
  const int bid = blockIdx.x;
  const int tid = threadIdx.x;

  if (bid >= 256) {                 // ---- transpose part ----
    float (*tile)[65] = (float(*)[65])smem;
    const int tb = bid - 256;
    const int e = tb >> 8;
    const int rem = tb & 255;
    const int f0 = (rem & 15) * 64, d0 = (rem >> 4) * 64;
    const float* wsrc = w + ((size_t)e << 20);
    uint16_t* wdst = wt + ((size_t)e << 20);
    const int r = tid >> 6, c = tid & 63;
#pragma unroll
    for (int i = 0; i < 16; ++i) {
      int row = i * 4 + r;
      tile[row][c] = wsrc[(size_t)(d0 + row) * DD + f0 + c];
    }
    __syncthreads();
#pragma unroll
    for (int i = 0; i < 16; ++i) {
      int frow = i * 4 + r;
      wdst[(size_t)(f0 + frow) * DD + d0 + c] = f2b(tile[c][frow]);
    }
    return;
  }

  // ---- gate part ----
  float* sgw = (float*)smem;                       // 32 KB, [d][e]
  float (*sx)[DD] = (float(*)[DD])(smem + 32768);  // 16 KB, one token per wave
  int* se1 = (int*)(smem + 49152);
  int* se2 = (int*)(smem + 49152 + 128);
#pragma unroll
  for (int i = 0; i < 32; ++i) sgw[i * 256 + tid] = gw[i * 256 + tid];
  const int t0 = bid * 32;
  const int wid = tid >> 6, lane = tid & 63;
  const int e = lane >> 3, dg = lane & 7;   // lane = (expert, d-group)

  for (int r = 0; r < 8; ++r) {
    const int tt = t0 + wid * 8 + r;
    const float4* xg = (const float4*)(x + (size_t)tt * DD);
    float4* sxv = (float4*)sx[wid];
    ushort4* xbv = (ushort4*)(xb + (size_t)tt * DD);
#pragma unroll
    for (int i = 0; i < 4; ++i) {
      float4 v = xg[i * 64 + lane];
      sxv[i * 64 + lane] = v;
      ushort4 h;
      h.x = f2b(v.x); h.y = f2b(v.y); h.z = f2b(v.z); h.w = f2b(v.w);
      xbv[i * 64 + lane] = h;
    }
    __syncthreads();

    const float* xr = sx[wid];
    double a0 = 0.0, a1 = 0.0, a2 = 0.0, a3 = 0.0;
#pragma unroll 8
    for (int k = 0; k < 128; k += 4) {
      int d = dg + k * 8;
      a0 += (double)xr[d]      * (double)sgw[d * 8 + e];
      a1 += (double)xr[d + 8]  * (double)sgw[(d + 8) * 8 + e];
      a2 += (double)xr[d + 16] * (double)sgw[(d + 16) * 8 + e];
      a3 += (double)xr[d + 24] * (double)sgw[(d + 24) * 8 + e];
    }
    double acc = (a0 + a1) + (a2 + a3);
#pragma unroll
    for (int off = 1; off < 8; off <<= 1) acc += __shfl_xor(acc, off);
    acc += (double)gb[e];
    double lg[8];
#pragma unroll
    for (int i = 0; i < 8; ++i) lg[i] = __shfl(acc, i * 8);
    if (lane == 0) {
      int e1 = 0; double m1 = lg[0];
#pragma unroll
      for (int i = 1; i < 8; ++i) if (lg[i] > m1) { m1 = lg[i]; e1 = i; }
      int e2 = 0; double m2 = -1.0e300;
#pragma unroll
      for (int i = 0; i < 8; ++i) if (i != e1 && lg[i] > m2) { m2 = lg[i]; e2 = i; }
      se1[wid * 8 + r] = e1;
      se2[wid * 8 + r] = e2;
    }
    __syncthreads();
  }

  if (tid < EN) {
    int cnt = 0;
#pragma unroll
    for (int i = 0; i < 32; ++i) cnt += (se1[i] == tid) + (se2[i] == tid);
    int base = atomicAdd(&counts[tid * CPAD], cnt);
    int* dst = lists + tid * T_TOK;
    for (int i = 0; i < 32; ++i) {
      if (se1[i] == tid) {
        if (WRITE_PIDX) pidx[2 * (t0 + i)] = tid * T_TOK + base;
        dst[base++] = t0 + i;
      }
      if (se2[i] == tid) {
        if (WRITE_PIDX) pidx[2 * (t0 + i) + 1] = tid * T_TOK + base;
        dst[base++] = t0 + i;
      }
    }
  }
}

// ---------- Phase 3: gathered per-expert GEMM, 128x128, BK=32, 4 blocks/CU ----------
// expert = orig&7 -> XCD-pinned (wt L2-resident); N fastest within expert for A sharing.
// 64-B rows: chunk-XOR swizzle chunk^=((row>>1)&3) -> 2-way bank alias (free, m136).
// Applied both-sides: pre-swizzled GLOBAL source k-offset + matching XOR on ds_read.
template <bool ATOMIC>
__global__ __launch_bounds__(256, 4) void expert_gemm_kernel(
    const uint16_t* __restrict__ xb, const uint16_t* __restrict__ wt,
    const float* __restrict__ eb, const int* __restrict__ counts,
    const int* __restrict__ lists, uint16_t* __restrict__ dst,
    float* __restrict__ dstf) {
  const int orig = blockIdx.x;
  const int e = orig & 7;               // expert == XCD
  const int rem = orig >> 3;            // 0..511
  const int m0 = (rem >> 3) * BM;
  const int n0 = (rem & 7) * BN;
  const int cnt = counts[e * CPAD];
  if (m0 >= cnt) return;
  int rows = cnt - m0; if (rows > BM) rows = BM;
  int offsE = 0;
  if (!ATOMIC) {
#pragma unroll
    for (int i = 0; i < EN; ++i) offsE += (i < e) ? counts[i * CPAD] : 0;
  }

  __shared__ uint16_t sA[2 * BM * BK];  // 16 KB dbuf, linear dest, data chunk-swizzled
  __shared__ uint16_t sB[2 * BN * BK];  // 16 KB
  __shared__ int toks[BM];

  const int tid = threadIdx.x;
  if (tid < BM) {
    int rr = tid < rows ? tid : 0;
    toks[tid] = lists[e * T_TOK + m0 + rr];
  }
  __syncthreads();

  const int lane = tid & 63;
  const int wid = tid >> 6;        // 0..3
  const int wm = wid >> 1;         // 0..1 (64 rows)
  const int wn = wid & 1;          // 0..1 (64 cols)

  v4f acc[4][4];
#pragma unroll
  for (int i = 0; i < 4; ++i)
#pragma unroll
    for (int j = 0; j < 4; ++j) acc[i][j] = (v4f){0.f, 0.f, 0.f, 0.f};

  // Staging: idx = i*256+tid (i<2); row = idx>>2; chunk = idx&3 (4 x 8-elem per 32-elem row).
  // Global k-offset pre-swizzled by ((row>>1)&3) so LDS chunk c holds k-group c^s(row).
  const uint16_t* aptr[2];
  const uint16_t* bptr[2];
  const uint16_t* wte = wt + ((size_t)e << 20) + (size_t)n0 * DD;
#pragma unroll
  for (int i = 0; i < 2; ++i) {
    int idx = i * 256 + tid;
    int row = idx >> 2;
    int koff = (((idx & 3) ^ ((row >> 1) & 3)) << 3);
    aptr[i] = xb + (size_t)toks[row] * DD + koff;
    bptr[i] = wte + (size_t)row * DD + koff;
  }

#define STAGE(buf, k0)                                                          \
  {                                                                             \
    _Pragma("unroll")                                                           \
    for (int i = 0; i < 2; ++i) {                                               \
      int idx = i * 256 + tid;                                                  \
      __builtin_amdgcn_global_load_lds(                                         \
          (const AS1 uint32_t*)(aptr[i] + (k0)),                                \
          (AS3 uint32_t*)(sA + (buf) * (BM * BK) + idx * 8), 16, 0, 0);         \
      __builtin_amdgcn_global_load_lds(                                         \
          (const AS1 uint32_t*)(bptr[i] + (k0)),                                \
          (AS3 uint32_t*)(sB + (buf) * (BN * BK) + idx * 8), 16, 0, 0);         \
    }                                                                           \
  }

  STAGE(0, 0);
  __syncthreads();

  const int c0 = lane >> 4;        // k-group 0..3
  const int rsel = lane & 15;
  int cur = 0;
  for (int kt = 0; kt < NT; ++kt) {
    if (kt + 1 < NT) STAGE(cur ^ 1, (kt + 1) * BK);   // prefetch flies under MFMA
    const uint16_t* a_base = sA + cur * (BM * BK);
    const uint16_t* b_base = sB + cur * (BN * BK);
    v8bf af[4], bfr[4];
#pragma unroll
    for (int m = 0; m < 4; ++m) {
      int row_a = wm * 64 + m * 16 + rsel;
      af[m] = *(const v8bf*)(a_base + row_a * BK + ((c0 ^ ((row_a >> 1) & 3)) << 3));
    }
#pragma unroll
    for (int n = 0; n < 4; ++n) {
      int row_b = wn * 64 + n * 16 + rsel;
      bfr[n] = *(const v8bf*)(b_base + row_b * BK + ((c0 ^ ((row_b >> 1) & 3)) << 3));
    }
#pragma unroll
    for (int m = 0; m < 4; ++m)
#pragma unroll
      for (int n = 0; n < 4; ++n)
        acc[m][n] = __builtin_amdgcn_mfma_f32_16x16x32_bf16(
            af[m], bfr[n], acc[m][n], 0, 0, 0);
    __syncthreads();   // drains this iter's prefetch + protects cur buf
    cur ^= 1;
  }
#undef STAGE

  // Epilogue: C/D layout col=lane&15, row=(lane>>4)*4+j.
  const int col = lane & 15, rq = lane >> 4;
  if (!ATOMIC) {
    uint16_t* base = dst + (size_t)(offsE + m0) * DD + n0 + wn * 64 + col;
#pragma unroll
    for (int m = 0; m < 4; ++m) {
#pragma unroll
      for (int j = 0; j < 4; ++j) {
        int trow = wm * 64 + m * 16 + rq * 4 + j;
        if (trow < rows) {
          uint16_t* orow = base + (size_t)trow * DD;
#pragma unroll
          for (int n = 0; n < 4; ++n) orow[n * 16] = f2b(acc[m][n][j]);
        }
      }
    }
  } else {
    float biasv[4];
#pragma unroll
    for (int n = 0; n < 4; ++n)
      biasv[n] = eb[e * DD + n0 + wn * 64 + n * 16 + col];
#pragma unroll
    for (int m = 0; m < 4; ++m) {
#pragma unroll
      for (int j = 0; j < 4; ++j) {
        int trow = wm * 64 + m * 16 + rq * 4 + j;
        if (trow < rows) {
          float* orow = dstf + (size_t)toks[trow] * DD + n0;
#pragma unroll
          for (int n = 0; n < 4; ++n)
            atomicAdd(orow + wn * 64 + n * 16 + col, acc[m][n][j] + biasv[n]);
        }
      }
    }
  }
}

// ---------- Phase 4: combine — out[t] = wsO[row(e1,p1)] + wsO[row(e2,p2)] + b1 + b2 ----------
__global__ __launch_bounds__(256) void combine_kernel(
    const uint16_t* __restrict__ wsO, const int* __restrict__ pidx,
    const int* __restrict__ counts, const float* __restrict__ eb,
    float* __restrict__ out) {
  __shared__ int soff[EN];
  const int tid = threadIdx.x;
  if (tid == 0) {
    int o = 0;
#pragma unroll
    for (int i = 0; i < EN; ++i) { soff[i] = o; o += counts[i * CPAD]; }
  }
  __syncthreads();
  const int t0 = blockIdx.x * 4;
#pragma unroll
  for (int r = 0; r < 4; ++r) {
    const int t = t0 + r;
    const int pi1 = pidx[2 * t], pi2 = pidx[2 * t + 1];
    const int e1 = pi1 >> 13, p1 = pi1 & (T_TOK - 1);
    const int e2 = pi2 >> 13, p2 = pi2 & (T_TOK - 1);
    ushort4 r1 = ((const ushort4*)(wsO + (size_t)(soff[e1] + p1) * DD))[tid];
    ushort4 r2 = ((const ushort4*)(wsO + (size_t)(soff[e2] + p2) * DD))[tid];
    v4f b1 = ((const v4f*)(eb + e1 * DD))[tid];
    v4f b2 = ((const v4f*)(eb + e2 * DD))[tid];
    v4f o;
    o[0] = b2f(r1.x) + b2f(r2.x) + b1[0] + b2[0];
    o[1] = b2f(r1.y) + b2f(r2.y) + b1[1] + b2[1];
    o[2] = b2f(r1.z) + b2f(r2.z) + b1[2] + b2[2];
    o[3] = b2f(r1.w) + b2f(r2.w) + b1[3] + b2[3];
    ((v4f*)(out + (size_t)t * DD))[tid] = o;
  }
}

extern "C" void kernel_launch(void* const* d_in, const int* in_sizes, int n_in,
                              void* d_out, int out_size, void* d_ws, size_t ws_size,
                              hipStream_t stream) {
  const float* x  = (const float*)d_in[0];   // [4,2048,1024] f32
  const float* gw = (const float*)d_in[1];   // [1024,8] f32
  const float* gb = (const float*)d_in[2];   // [8] f32
  const float* ew = (const float*)d_in[3];   // [8,1024,1024] f32
  const float* ebias = (const float*)d_in[4];// [8,1024] f32
  float* out = (float*)d_out;                // [4,2048,1024] f32

  uint8_t* ws = (uint8_t*)d_ws;
  int* counts = (int*)ws;                                    // 512 B
  int* lists  = (int*)(ws + 512);                            // 256 KiB
  int* pidx   = (int*)(ws + 512 + 262144);                   // 64 KiB
  uint16_t* xb = (uint16_t*)(ws + 512 + 262144 + 65536);     // 16 MiB
  uint16_t* wt = (uint16_t*)(ws + 512 + 262144 + 65536 + 16777216); // 16 MiB
  uint16_t* wsO = (uint16_t*)(ws + 512 + 262144 + 65536 + 2 * 16777216); // 32 MiB bf16
  const size_t need = 512ull + 262144 + 65536 + 2 * 16777216 +
                      (size_t)2 * T_TOK * DD * sizeof(uint16_t);
  const bool use_ws = ws_size >= need;

  hipMemsetAsync(counts, 0, 512, stream);
  if (use_ws) {
    prep_kernel<true><<<2304, 256, 49408, stream>>>(
        x, gw, gb, xb, counts, lists, pidx, ew, wt);
    expert_gemm_kernel<false><<<NWG, 256, 0, stream>>>(
        xb, wt, ebias, counts, lists, wsO, nullptr);
    combine_kernel<<<T_TOK / 4, 256, 0, stream>>>(wsO, pidx, counts, ebias, out);
  } else {
    hipMemsetAsync(d_out, 0, (size_t)out_size * sizeof(float), stream);
    prep_kernel<false><<<2304, 256, 49408, stream>>>(
        x, gw, gb, xb, counts, lists, pidx, ew, wt);
    expert_gemm_kernel<true><<<NWG, 256, 0, stream>>>(
        xb, wt, ebias, counts, lists, nullptr, out);
  }
}